// Round 4
// baseline (209.233 us; speedup 1.0000x reference)
//
#include <hip/hip_runtime.h>
#include <hip/hip_bf16.h>
#include <stdint.h>

#define NP 30000
#define BBINS 80
#define INCH 16
#define OUTCH 32
#define KDIM 1280       // BBINS*INCH
#define NDIM 512        // OUTCH*TBINS
#define KSTEPS 40       // KDIM/32
#define NROWS (NP * BBINS)   // 2,400,000
#define MTILES 469      // ceil(NP/64)

typedef __bf16 bf16x8 __attribute__((ext_vector_type(8)));
typedef __bf16 bf16x4 __attribute__((ext_vector_type(4)));
typedef float f32x4 __attribute__((ext_vector_type(4)));

__device__ __forceinline__ void async_ld16(const void* g, void* l) {
    __builtin_amdgcn_global_load_lds(
        (const __attribute__((address_space(1))) unsigned int*)g,
        (__attribute__((address_space(3))) unsigned int*)l,
        16, 0, 0);
}

// ---------------------------------------------------------------------------
// Prep: PW[kc][n][qs][e] bf16 with chunk-XOR swizzle qs ^ ((n>>1)&3), where
// lw[k][n] = W[(b+5t)%80][c][o], k=b*16+c, n=o*16+t. (unchanged, proven)
// ---------------------------------------------------------------------------
__global__ void prep_weights(const float* __restrict__ w, __bf16* __restrict__ pw) {
    int gid = blockIdx.x * 256 + threadIdx.x;           // 655360 total
    int e  = gid & 7;
    int qs = (gid >> 3) & 3;
    int n  = (gid >> 5) & 511;
    int kc = gid >> 14;                                  // 0..39
    int kp = kc * 32 + ((qs ^ ((n >> 1) & 3)) << 3) + e; // 0..1279
    int b = kp >> 4, c = kp & 15;
    int o = n >> 4,  t = n & 15;
    int bid = (b + 5 * t) % BBINS;
    pw[gid] = (__bf16)w[(bid * INCH + c) * OUTCH + o];
}

// ---------------------------------------------------------------------------
// Gather: FOUR lanes per (patch,bin) row, BUT only the quad leader (q==0)
// loads the 6 metadata words (was 4x redundant = 24 of 40 lane-addresses
// per row); __shfl broadcasts to the quad. Meta loads + h stores are
// nontemporal so the 75MB h stream doesn't evict x (1.9MB, must stay L2-
// resident for the random gathers). Discriminator: if flat, gather is
// line/MSHR-bound, not request-issue-bound.
// ---------------------------------------------------------------------------
__global__ __launch_bounds__(256) void gather_h(
    const float* __restrict__ x,
    const int*   __restrict__ cidx,
    const float* __restrict__ cval,
    __bf16* __restrict__ h) {
    const int gid  = blockIdx.x * 256 + threadIdx.x;     // 9,600,000 total
    const int r    = gid >> 2;                           // row 0..NROWS-1
    const int q    = gid & 3;                            // channel quad
    const int lane = threadIdx.x & 63;

    int i0 = 0, i1 = 0, i2 = 0;
    float v0 = 0.f, v1 = 0.f, v2 = 0.f;
    if (q == 0) {
        const int r3 = r * 3;
        i0 = __builtin_nontemporal_load(cidx + r3 + 0);
        i1 = __builtin_nontemporal_load(cidx + r3 + 1);
        i2 = __builtin_nontemporal_load(cidx + r3 + 2);
        v0 = __builtin_nontemporal_load(cval + r3 + 0);
        v1 = __builtin_nontemporal_load(cval + r3 + 1);
        v2 = __builtin_nontemporal_load(cval + r3 + 2);
    }
    const int src = lane & 60;                           // quad leader lane
    i0 = __shfl(i0, src); i1 = __shfl(i1, src); i2 = __shfl(i2, src);
    v0 = __shfl(v0, src); v1 = __shfl(v1, src); v2 = __shfl(v2, src);

    const float4 a = *(const float4*)(x + (size_t)i0 * 16 + q * 4);
    const float4 b = *(const float4*)(x + (size_t)i1 * 16 + q * 4);
    const float4 c = *(const float4*)(x + (size_t)i2 * 16 + q * 4);
    bf16x4 hv;
    hv[0] = (__bf16)(v0 * a.x + v1 * b.x + v2 * c.x);
    hv[1] = (__bf16)(v0 * a.y + v1 * b.y + v2 * c.y);
    hv[2] = (__bf16)(v0 * a.z + v1 * b.z + v2 * c.z);
    hv[3] = (__bf16)(v0 * a.w + v1 * b.w + v2 * c.w);
    union { bf16x4 h4; unsigned long long u; } cvt;
    cvt.h4 = hv;
    __builtin_nontemporal_store(cvt.u,
        (unsigned long long*)((char*)h + (size_t)gid * 8));
}

// ---------------------------------------------------------------------------
// GEMM + max-over-t.  R3 diagnosis: occupancy 18.5% == 470 blocks / 256 CU
// exactly -> GRID-STARVED (resources allowed ~5 blocks/CU). The ~1500cy
// per-kstep vmcnt-drain stall had no co-resident block to overlap with.
// Fix: 64x256 tile -> 938 blocks (3.7/CU). 4 waves, wave tile 64x64 =
// 4x4 mfma_f32_16x16x32_bf16. LDS 20KB (A 4KB + B 16KB). A-fetch
// duplication unchanged (ncol=2); pw duplication x2 is free (L2-resident).
// Skeleton + both conflict-free swizzles unchanged (proven R1-R3).
// ---------------------------------------------------------------------------
__global__ __launch_bounds__(256, 3) void gemm_max(
    const __bf16* __restrict__ h,
    const __bf16* __restrict__ pw,
    float* __restrict__ out) {

    __shared__ __align__(16) __bf16 Alds[64 * 32];       // 4 KB  (row stride 64 B)
    __shared__ __align__(16) __bf16 Blds[256 * 32];      // 16 KB (n stride 64 B)

    const int bid  = blockIdx.x;
    const int mb   = bid >> 1;           // 0..468
    const int ncol = bid & 1;            // 0/1
    const int mbase = mb * 64;

    const int tid  = threadIdx.x;
    const int lane = tid & 63;
    const int wave = tid >> 6;           // 0..3 = column group within block

    const int ml = lane & 15, q = lane >> 4;
    const int f = (ml >> 1) & 3;                         // bank-group swizzle
    int a_off[4], b_off[4];
#pragma unroll
    for (int i = 0; i < 4; ++i)
        a_off[i] = (i * 16 + ml) * 64 + ((q ^ f) << 4);
#pragma unroll
    for (int j = 0; j < 4; ++j) {
        int nl = wave * 64 + j * 16 + ml;
        b_off[j] = nl * 64 + ((q ^ f) << 4);
    }

    f32x4 acc[4][4];
#pragma unroll
    for (int i = 0; i < 4; ++i)
#pragma unroll
        for (int j = 0; j < 4; ++j)
            acc[i][j] = (f32x4){0.f, 0.f, 0.f, 0.f};

    const char* hB  = (const char*)h;
    const char* pwB = (const char*)pw + ncol * 16384 + tid * 16;
    int rg = mbase + (tid >> 2);         // row 0..63 of tile
    if (rg > NP - 1) rg = NP - 1;
    // pre-swizzled source chunk: LDS slot (tid&3) of local row (tid>>2) holds
    // source chunk (tid&3) ^ ((localrow>>1)&3) = (tid&3) ^ ((tid>>3)&3)
    // (mbase % 64 == 0 so global and local row swizzle terms agree)
    const int swz = ((tid & 3) ^ ((tid >> 3) & 3)) * 16;
    const char* aSrc = hB + (size_t)rg * 2560 + swz;
    char* aDst = (char*)Alds + tid * 16;
    char* bDst = (char*)Blds + tid * 16;

    for (int kc = 0; kc < KSTEPS; ++kc) {
        const char* bs = pwB + kc * 32768;
#pragma unroll
        for (int i = 0; i < 4; ++i)
            async_ld16(bs + i * 4096, bDst + i * 4096);
        async_ld16(aSrc + kc * 64, aDst);
        __syncthreads();

        bf16x8 af[4], bfr[4];
#pragma unroll
        for (int i = 0; i < 4; ++i)
            af[i] = *(const bf16x8*)((const char*)Alds + a_off[i]);
#pragma unroll
        for (int j = 0; j < 4; ++j)
            bfr[j] = *(const bf16x8*)((const char*)Blds + b_off[j]);
#pragma unroll
        for (int i = 0; i < 4; ++i)
#pragma unroll
            for (int j = 0; j < 4; ++j)
                acc[i][j] = __builtin_amdgcn_mfma_f32_16x16x32_bf16(
                    af[i], bfr[j], acc[i][j], 0, 0, 0);
        __syncthreads();
    }

    const int rgrp = lane >> 4;
    const int tl   = lane & 15;
#pragma unroll
    for (int i = 0; i < 4; ++i) {
#pragma unroll
        for (int j = 0; j < 4; ++j) {
            float v0 = acc[i][j][0], v1 = acc[i][j][1];
            float v2 = acc[i][j][2], v3 = acc[i][j][3];
#pragma unroll
            for (int off = 1; off < 16; off <<= 1) {
                v0 = fmaxf(v0, __shfl_xor(v0, off));
                v1 = fmaxf(v1, __shfl_xor(v1, off));
                v2 = fmaxf(v2, __shfl_xor(v2, off));
                v3 = fmaxf(v3, __shfl_xor(v3, off));
            }
            if (tl == 0) {
                const int o  = ncol * 16 + wave * 4 + j;
                const int pr = mbase + i * 16 + rgrp * 4;
                if (pr + 0 < NP) out[(pr + 0) * 32 + o] = v0;
                if (pr + 1 < NP) out[(pr + 1) * 32 + o] = v1;
                if (pr + 2 < NP) out[(pr + 2) * 32 + o] = v2;
                if (pr + 3 < NP) out[(pr + 3) * 32 + o] = v3;
            }
        }
    }
}

extern "C" void kernel_launch(void* const* d_in, const int* in_sizes, int n_in,
                              void* d_out, int out_size, void* d_ws, size_t ws_size,
                              hipStream_t stream) {
    const float* x    = (const float*)d_in[0];
    const int*   cidx = (const int*)d_in[1];
    const float* cval = (const float*)d_in[2];
    const float* w    = (const float*)d_in[3];
    float* out = (float*)d_out;

    __bf16* pw = (__bf16*)d_ws;                               // 1.31 MB
    __bf16* h  = (__bf16*)((char*)d_ws + (2 << 20));          // 76.8 MB @ +2MB

    hipLaunchKernelGGL(prep_weights, dim3(2560), dim3(256), 0, stream, w, pw);
    hipLaunchKernelGGL(gather_h, dim3(NROWS * 4 / 256), dim3(256), 0, stream,
                       x, cidx, cval, h);
    hipLaunchKernelGGL(gemm_max, dim3(MTILES * 2), dim3(256), 0, stream,
                       h, (const __bf16*)pw, out);
}

// Round 5
// 190.084 us; speedup vs baseline: 1.1007x; 1.1007x over previous
//
#include <hip/hip_runtime.h>
#include <hip/hip_bf16.h>
#include <stdint.h>

#define NP 30000
#define BBINS 80
#define INCH 16
#define OUTCH 32
#define KDIM 1280       // BBINS*INCH
#define NDIM 512        // OUTCH*TBINS
#define KSTEPS2 20      // KDIM/64  (BK=64)
#define NROWS (NP * BBINS)   // 2,400,000

typedef __bf16 bf16x8 __attribute__((ext_vector_type(8)));
typedef __bf16 bf16x4 __attribute__((ext_vector_type(4)));
typedef float f32x4 __attribute__((ext_vector_type(4)));

__device__ __forceinline__ void async_ld16(const void* g, void* l) {
    __builtin_amdgcn_global_load_lds(
        (const __attribute__((address_space(1))) unsigned int*)g,
        (__attribute__((address_space(3))) unsigned int*)l,
        16, 0, 0);
}

// ---------------------------------------------------------------------------
// Prep: PW[kc][n][qs][e] bf16 with chunk-XOR swizzle qs ^ ((n>>1)&3), where
// lw[k][n] = W[(b+5t)%80][c][o], k=b*16+c, n=o*16+t. (unchanged, proven)
// ---------------------------------------------------------------------------
__global__ void prep_weights(const float* __restrict__ w, __bf16* __restrict__ pw) {
    int gid = blockIdx.x * 256 + threadIdx.x;           // 655360 total
    int e  = gid & 7;
    int qs = (gid >> 3) & 3;
    int n  = (gid >> 5) & 511;
    int kc = gid >> 14;                                  // 0..39
    int kp = kc * 32 + ((qs ^ ((n >> 1) & 3)) << 3) + e; // 0..1279
    int b = kp >> 4, c = kp & 15;
    int o = n >> 4,  t = n & 15;
    int bid = (b + 5 * t) % BBINS;
    pw[gid] = (__bf16)w[(bid * INCH + c) * OUTCH + o];
}

// ---------------------------------------------------------------------------
// Gather: FOUR lanes per (patch,bin) row; only the quad leader (q==0) loads
// the 6 metadata words (cuts VMEM lane-requests/row 40 -> 22), __shfl
// broadcast to the quad. Metadata loads stay nontemporal (streamed once);
// the h STORE is a plain store (R4's nt-store may have evicted h from L2
// and doubled gemm FETCH - reverted).
// ---------------------------------------------------------------------------
__global__ __launch_bounds__(256) void gather_h(
    const float* __restrict__ x,
    const int*   __restrict__ cidx,
    const float* __restrict__ cval,
    __bf16* __restrict__ h) {
    const int gid  = blockIdx.x * 256 + threadIdx.x;     // 9,600,000 total
    const int r    = gid >> 2;                           // row 0..NROWS-1
    const int q    = gid & 3;                            // channel quad
    const int lane = threadIdx.x & 63;

    int i0 = 0, i1 = 0, i2 = 0;
    float v0 = 0.f, v1 = 0.f, v2 = 0.f;
    if (q == 0) {
        const int r3 = r * 3;
        i0 = __builtin_nontemporal_load(cidx + r3 + 0);
        i1 = __builtin_nontemporal_load(cidx + r3 + 1);
        i2 = __builtin_nontemporal_load(cidx + r3 + 2);
        v0 = __builtin_nontemporal_load(cval + r3 + 0);
        v1 = __builtin_nontemporal_load(cval + r3 + 1);
        v2 = __builtin_nontemporal_load(cval + r3 + 2);
    }
    const int src = lane & 60;                           // quad leader lane
    i0 = __shfl(i0, src); i1 = __shfl(i1, src); i2 = __shfl(i2, src);
    v0 = __shfl(v0, src); v1 = __shfl(v1, src); v2 = __shfl(v2, src);

    const float4 a = *(const float4*)(x + (size_t)i0 * 16 + q * 4);
    const float4 b = *(const float4*)(x + (size_t)i1 * 16 + q * 4);
    const float4 c = *(const float4*)(x + (size_t)i2 * 16 + q * 4);
    bf16x4 hv;
    hv[0] = (__bf16)(v0 * a.x + v1 * b.x + v2 * c.x);
    hv[1] = (__bf16)(v0 * a.y + v1 * b.y + v2 * c.y);
    hv[2] = (__bf16)(v0 * a.z + v1 * b.z + v2 * c.z);
    hv[3] = (__bf16)(v0 * a.w + v1 * b.w + v2 * c.w);
    *(bf16x4*)((char*)h + (size_t)gid * 8) = hv;
}

// ---------------------------------------------------------------------------
// GEMM + max-over-t.  Block: 256 threads (4 waves), tile 128 rows x 256 cols.
// Wave grid 2x2; wave tile 64x128. R3 skeleton + swizzles + bid mapping
// (m-tiles grouped by 8 so the two ncol blocks of an m-tile are 8 apart ->
// SAME XCD -> A's second read hits that XCD's L2; R4's adjacent pairing
// doubled FETCH - kept R3 mapping).
//
// ONLY change vs R3 (58.3us, MfmaUtil 27.6%): BK 32 -> 64. R3's per-kstep
// budget was ~1740cy/block = 256cy MFMA + ~440cy staging BW + ~1000cy fixed
// latency/barrier. BK=64 halves the k-step count (20 iters): fixed term
// amortized over 2x MFMA. LDS 48KB (A 16KB + B 32KB), 2 blocks/CU = 96KB.
// Both halves (ks=0,1) of each k-step reuse the EXACT proven 64B-row layout
// and conflict-free swizzle; staging = 12 async_ld16/thread/kstep.
// ---------------------------------------------------------------------------
__global__ __launch_bounds__(256, 2) void gemm_max(
    const __bf16* __restrict__ h,
    const __bf16* __restrict__ pw,
    float* __restrict__ out) {

    __shared__ __align__(16) __bf16 Alds[2 * 128 * 32];  // 16 KB: [ks][row][32k]
    __shared__ __align__(16) __bf16 Blds[2 * 256 * 32];  // 32 KB: [ks][n][32k]

    const int bid = blockIdx.x;
    const int m    = (bid >> 4) * 8 + (bid & 7);         // 0..239
    const int ncol = (bid >> 3) & 1;                     // 0/1
    if (m >= 235) return;                                // 10 dead pad blocks
    const int mbase = m * 128;

    const int tid  = threadIdx.x;
    const int lane = tid & 63;
    const int wave = tid >> 6;
    const int wave_mrow = wave >> 1;     // 0..1
    const int wave_ncol = wave & 1;      // 0..1

    const int ml = lane & 15, q = lane >> 4;
    const int f = (ml >> 1) & 3;                         // bank-group swizzle
    int a_off[4], b_off[8];
#pragma unroll
    for (int i = 0; i < 4; ++i)
        a_off[i] = (wave_mrow * 64 + i * 16 + ml) * 64 + ((q ^ f) << 4);
#pragma unroll
    for (int j = 0; j < 8; ++j) {
        int nl = wave_ncol * 128 + j * 16 + ml;
        b_off[j] = nl * 64 + ((q ^ f) << 4);
    }

    f32x4 acc[4][8];
#pragma unroll
    for (int i = 0; i < 4; ++i)
#pragma unroll
        for (int j = 0; j < 8; ++j)
            acc[i][j] = (f32x4){0.f, 0.f, 0.f, 0.f};

    const char* hB  = (const char*)h;
    const char* pwB = (const char*)pw + ncol * 16384 + tid * 16;
    int rg0 = mbase + (tid >> 2);        // rows 0..63 of tile
    int rg1 = rg0 + 64;                  // rows 64..127
    if (rg0 > NP - 1) rg0 = NP - 1;
    if (rg1 > NP - 1) rg1 = NP - 1;
    // pre-swizzled source chunk: LDS slot (tid&3) of row (tid>>2) must hold
    // source chunk (tid&3) ^ ((row>>1)&3) = (tid&3) ^ ((tid>>3)&3)
    const int swz = ((tid & 3) ^ ((tid >> 3) & 3)) * 16;
    const char* aSrc0 = hB + (size_t)rg0 * 2560 + swz;
    const char* aSrc1 = hB + (size_t)rg1 * 2560 + swz;
    char* aDst = (char*)Alds + tid * 16;
    char* bDst = (char*)Blds + tid * 16;

    for (int kc = 0; kc < KSTEPS2; ++kc) {
        // B: two consecutive 32k-chunks (ks=0,1) of 512 n each; our ncol
        // half is 16KB per ks. pw kc-chunk stride = 32768 B.
        const char* bs = pwB + kc * 65536;
#pragma unroll
        for (int i = 0; i < 4; ++i)
            async_ld16(bs + i * 4096, bDst + i * 4096);              // ks=0
#pragma unroll
        for (int i = 0; i < 4; ++i)
            async_ld16(bs + 32768 + i * 4096, bDst + 16384 + i * 4096); // ks=1
        // A: row k-bytes [kc*128, kc*128+128); 64B per ks half.
        async_ld16(aSrc0 + kc * 128,      aDst);                     // ks0 r0-63
        async_ld16(aSrc1 + kc * 128,      aDst + 4096);              // ks0 r64-127
        async_ld16(aSrc0 + kc * 128 + 64, aDst + 8192);              // ks1 r0-63
        async_ld16(aSrc1 + kc * 128 + 64, aDst + 12288);             // ks1 r64-127
        __syncthreads();

#pragma unroll
        for (int ks = 0; ks < 2; ++ks) {
            const char* A = (const char*)Alds + ks * 8192;
            const char* B = (const char*)Blds + ks * 16384;
            bf16x8 af[4], bfr[8];
#pragma unroll
            for (int i = 0; i < 4; ++i)
                af[i] = *(const bf16x8*)(A + a_off[i]);
#pragma unroll
            for (int j = 0; j < 8; ++j)
                bfr[j] = *(const bf16x8*)(B + b_off[j]);
#pragma unroll
            for (int i = 0; i < 4; ++i)
#pragma unroll
                for (int j = 0; j < 8; ++j)
                    acc[i][j] = __builtin_amdgcn_mfma_f32_16x16x32_bf16(
                        af[i], bfr[j], acc[i][j], 0, 0, 0);
        }
        __syncthreads();
    }

    const int rgrp = lane >> 4;
    const int tl   = lane & 15;
#pragma unroll
    for (int i = 0; i < 4; ++i) {
#pragma unroll
        for (int j = 0; j < 8; ++j) {
            float v0 = acc[i][j][0], v1 = acc[i][j][1];
            float v2 = acc[i][j][2], v3 = acc[i][j][3];
#pragma unroll
            for (int off = 1; off < 16; off <<= 1) {
                v0 = fmaxf(v0, __shfl_xor(v0, off));
                v1 = fmaxf(v1, __shfl_xor(v1, off));
                v2 = fmaxf(v2, __shfl_xor(v2, off));
                v3 = fmaxf(v3, __shfl_xor(v3, off));
            }
            if (tl == 0) {
                const int o  = ncol * 16 + wave_ncol * 8 + j;
                const int pr = mbase + wave_mrow * 64 + i * 16 + rgrp * 4;
                if (pr + 0 < NP) out[(pr + 0) * 32 + o] = v0;
                if (pr + 1 < NP) out[(pr + 1) * 32 + o] = v1;
                if (pr + 2 < NP) out[(pr + 2) * 32 + o] = v2;
                if (pr + 3 < NP) out[(pr + 3) * 32 + o] = v3;
            }
        }
    }
}

extern "C" void kernel_launch(void* const* d_in, const int* in_sizes, int n_in,
                              void* d_out, int out_size, void* d_ws, size_t ws_size,
                              hipStream_t stream) {
    const float* x    = (const float*)d_in[0];
    const int*   cidx = (const int*)d_in[1];
    const float* cval = (const float*)d_in[2];
    const float* w    = (const float*)d_in[3];
    float* out = (float*)d_out;

    __bf16* pw = (__bf16*)d_ws;                               // 1.31 MB
    __bf16* h  = (__bf16*)((char*)d_ws + (2 << 20));          // 76.8 MB @ +2MB

    hipLaunchKernelGGL(prep_weights, dim3(2560), dim3(256), 0, stream, w, pw);
    hipLaunchKernelGGL(gather_h, dim3(NROWS * 4 / 256), dim3(256), 0, stream,
                       x, cidx, cval, h);
    hipLaunchKernelGGL(gemm_max, dim3(480), dim3(256), 0, stream,
                       h, (const __bf16*)pw, out);
}